// Round 9
// baseline (633.474 us; speedup 1.0000x reference)
//
#include <hip/hip_runtime.h>
#include <math.h>

#define HW    1024
#define CIN   1024
#define CCTX  28
#define CALL  1052
#define COUT  2048
#define CCHNK 512

typedef _Float16 half8   __attribute__((ext_vector_type(8)));
typedef _Float16 half4_t __attribute__((ext_vector_type(4)));
typedef _Float16 half2_t __attribute__((ext_vector_type(2)));
typedef __fp16   fp16x2  __attribute__((ext_vector_type(2)));
typedef float    f32x4   __attribute__((ext_vector_type(4)));

// split a into hi (top-10-bit mantissa, exact in f16) + lo, packed pairwise.
__device__ __forceinline__ void split2(float a0, float a1, half2_t& h, half2_t& l) {
    float h0 = __uint_as_float(__float_as_uint(a0) & 0xFFFFE000u);
    float h1 = __uint_as_float(__float_as_uint(a1) & 0xFFFFE000u);
    fp16x2 hp = __builtin_amdgcn_cvt_pkrtz(h0, h1);
    fp16x2 lp = __builtin_amdgcn_cvt_pkrtz(a0 - h0, a1 - h1);
    h = __builtin_bit_cast(half2_t, hp);
    l = __builtin_bit_cast(half2_t, lp);
}
__device__ __forceinline__ void split4(float4 v, half4_t& h, half4_t& l) {
    half2_t ha, la, hb, lb;
    split2(v.x, v.y, ha, la);
    split2(v.z, v.w, hb, lb);
    h = __builtin_shufflevector(ha, hb, 0, 1, 2, 3);
    l = __builtin_shufflevector(la, lb, 0, 1, 2, 3);
}
__device__ __forceinline__ float f4get(const float4& v, int e) {
    return e == 0 ? v.x : e == 1 ? v.y : e == 2 ? v.z : v.w;
}

// ---------------------------------------------------------------------------
// Kernel 1a/1b: pnorm partials + combine
// ---------------------------------------------------------------------------
__global__ void pnorm_part(const float* __restrict__ src, const float* __restrict__ tgt,
                           float* __restrict__ parts) {
    int img = blockIdx.x, pb = blockIdx.y, part = blockIdx.z;
    int p = pb * 64 + threadIdx.x;
    const float* feat = ((img < 4) ? src + (size_t)img * CIN * HW
                                   : tgt + (size_t)(img - 4) * CIN * HW)
                        + (size_t)part * 256 * HW + p;
    float a4[4] = {};
    for (int c = 0; c < 256; c += 8) {
        float v[8];
#pragma unroll
        for (int j = 0; j < 8; ++j) v[j] = feat[(size_t)(c + j) * HW];
#pragma unroll
        for (int j = 0; j < 8; ++j) a4[j & 3] = fmaf(v[j], v[j], a4[j & 3]);
    }
    parts[(size_t)part * 8192 + img * 1024 + p] = (a4[0] + a4[1]) + (a4[2] + a4[3]);
}
__global__ void pnorm_combine(const float* __restrict__ parts, float* __restrict__ pnorm) {
    int img = blockIdx.x;
    int p = blockIdx.y * 64 + threadIdx.x;
    float s = parts[img * 1024 + p] + parts[8192 + img * 1024 + p]
            + parts[16384 + img * 1024 + p] + parts[24576 + img * 1024 + p];
    pnorm[img * HW + p] = fmaxf(sqrtf(s), 1e-12f);
}

// ---------------------------------------------------------------------------
// Kernel 2: shifted local correlations (round-3 proven form — plain loop)
// ---------------------------------------------------------------------------
__global__ void ctx_kernel(const float* __restrict__ src, const float* __restrict__ tgt,
                           const float* __restrict__ pnorm, float* __restrict__ ctx) {
    int img = blockIdx.x;
    int y = blockIdx.y;
    int tid = threadIdx.x;
    int o = tid >> 5;
    int x = tid & 31;
    const float* feat = (img < 4) ? src + (size_t)img * CIN * HW
                                  : tgt + (size_t)(img - 4) * CIN * HW;
    int g = o / 7, i = o % 7;
    int r, c;
    if (g == 0)      { r = i; c = i; }
    else if (g == 1) { r = i; c = 3; }
    else if (g == 2) { r = i; c = 6 - i; }
    else             { r = 3; c = i; }
    int y2 = y + r - 3, x2 = x + c - 3;
    int p = y * 32 + x;
    float outv = 0.f;
    if (y2 >= 0 && y2 < 32 && x2 >= 0 && x2 < 32) {
        int p2 = y2 * 32 + x2;
        const float* f0 = feat + p;
        const float* f1 = feat + p2;
        float acc = 0.f;
        for (int ch = 0; ch < CIN; ++ch)
            acc = fmaf(f0[(size_t)ch * HW], f1[(size_t)ch * HW], acc);
        outv = acc / (pnorm[img * HW + p] * pnorm[img * HW + p2]);
    }
    ctx[((size_t)img * CCTX + o) * HW + p] = outv;
}

// ---------------------------------------------------------------------------
// Kernel 3: conv via MFMA. Block tile 64 pix x 256 chan, 4 waves (64x64 each).
// X(pix,k) staged+split via LDS transpose; W(256,k) staged+split ONCE per
// block (shared). Single-buffer BK=32, 2 barriers/tile. Output: planar f16
// hi/lo ychunk [img][pix][512].  grid (2 cb, 16 pb, 8 img), 256 thr.
// ---------------------------------------------------------------------------
template <bool FIRST>
__global__ __launch_bounds__(256) void conv_mfma(
    const float* __restrict__ src, const float* __restrict__ tgt,
    const float* __restrict__ ctxb, const float* __restrict__ w,
    const float* __restrict__ bias, _Float16* __restrict__ yh,
    _Float16* __restrict__ yl, float* __restrict__ nrm_parts, int c0) {
    __shared__ __align__(16) char smem[51200];
    _Float16* Ah = (_Float16*)smem;        // [64][40]
    _Float16* Al = Ah + 2560;
    _Float16* Wh = Al + 2560;              // [256][40]
    _Float16* Wl = Wh + 10240;

    int cb = blockIdx.x, pb = blockIdx.y, img = blockIdx.z;
    int n0 = pb * 64;
    int m0g = c0 + cb * 256;
    const float* feat = (img < 4) ? src + (size_t)img * CIN * HW
                                  : tgt + (size_t)(img - 4) * CIN * HW;
    const float* ctxi = ctxb + (size_t)img * CCTX * HW;
    int tid = threadIdx.x;
    int lane = tid & 63, wv = tid >> 6;
    int frow = lane & 15, kg = (lane >> 4) * 8;
    int aq = tid & 15, ar = tid >> 4;      // A stage: pix-quad, k-pair

    float4 xa[2], xw[8];
    auto stage_regs = [&](int k0) {
#pragma unroll
        for (int j = 0; j < 2; ++j) {
            int k = k0 + ar * 2 + j;
            if (k < CIN)       xa[j] = *(const float4*)(feat + (size_t)k * HW + n0 + aq * 4);
            else if (k < CALL) xa[j] = *(const float4*)(ctxi + (size_t)(k - CIN) * HW + n0 + aq * 4);
            else               xa[j] = make_float4(0.f, 0.f, 0.f, 0.f);
        }
#pragma unroll
        for (int i = 0; i < 8; ++i) {
            int k = k0 + i * 4;
            xw[i] = (k + 4 <= CALL) ? *(const float4*)(w + (size_t)(m0g + tid) * CALL + k)
                                    : make_float4(0.f, 0.f, 0.f, 0.f);
        }
    };
    auto write_lds = [&]() {
#pragma unroll
        for (int p = 0; p < 4; ++p) {
            half2_t h, l;
            split2(f4get(xa[0], p), f4get(xa[1], p), h, l);
            int row = aq * 4 + p;
            *(half2_t*)(Ah + row * 40 + ar * 2) = h;
            *(half2_t*)(Al + row * 40 + ar * 2) = l;
        }
#pragma unroll
        for (int i = 0; i < 8; ++i) {
            half4_t h, l;
            split4(xw[i], h, l);
            *(half4_t*)(Wh + tid * 40 + i * 4) = h;
            *(half4_t*)(Wl + tid * 40 + i * 4) = l;
        }
    };

    f32x4 acc[4][4] = {};
    const int NT = 33;
    stage_regs(0); write_lds();
    __syncthreads();
    for (int t = 0; t < NT; ++t) {
        half8 afh[4], afl[4], bfh[4], bfl[4];
#pragma unroll
        for (int fm = 0; fm < 4; ++fm) {
            int r = fm * 16 + frow;
            afh[fm] = *(const half8*)(Ah + r * 40 + kg);
            afl[fm] = *(const half8*)(Al + r * 40 + kg);
        }
#pragma unroll
        for (int fn = 0; fn < 4; ++fn) {
            int r = wv * 64 + fn * 16 + frow;
            bfh[fn] = *(const half8*)(Wh + r * 40 + kg);
            bfl[fn] = *(const half8*)(Wl + r * 40 + kg);
        }
        if (t + 1 < NT) stage_regs((t + 1) * 32);
#pragma unroll
        for (int fm = 0; fm < 4; ++fm)
#pragma unroll
            for (int fn = 0; fn < 4; ++fn) {
                acc[fm][fn] = __builtin_amdgcn_mfma_f32_16x16x32_f16(afh[fm], bfh[fn], acc[fm][fn], 0, 0, 0);
                acc[fm][fn] = __builtin_amdgcn_mfma_f32_16x16x32_f16(afh[fm], bfl[fn], acc[fm][fn], 0, 0, 0);
                acc[fm][fn] = __builtin_amdgcn_mfma_f32_16x16x32_f16(afl[fm], bfh[fn], acc[fm][fn], 0, 0, 0);
            }
        __syncthreads();
        if (t + 1 < NT) write_lds();
        __syncthreads();
    }

    // epilogue: bias+relu, per-pixel sum-sq partials, planar hi/lo bounce.
    float bv[4];
#pragma unroll
    for (int fn = 0; fn < 4; ++fn) bv[fn] = bias[m0g + wv * 64 + fn * 16 + frow];

    float* nsf = (float*)smem;                     // [4][64]
    _Float16* yb = (_Float16*)(smem + 2048);       // [64][264]
    float psum[4][4] = {};
#pragma unroll
    for (int fm = 0; fm < 4; ++fm)
#pragma unroll
        for (int fn = 0; fn < 4; ++fn)
#pragma unroll
            for (int r = 0; r < 4; ++r) {
                float v = fmaxf(acc[fm][fn][r] + bv[fn], 0.f);
                acc[fm][fn][r] = v;
                psum[fm][r] = fmaf(v, v, psum[fm][r]);
            }
#pragma unroll
    for (int off = 1; off <= 8; off <<= 1)
#pragma unroll
        for (int fm = 0; fm < 4; ++fm)
#pragma unroll
            for (int r = 0; r < 4; ++r)
                psum[fm][r] = psum[fm][r] + __shfl_xor(psum[fm][r], off);
    if (frow == 0) {
#pragma unroll
        for (int fm = 0; fm < 4; ++fm)
#pragma unroll
            for (int r = 0; r < 4; ++r)
                nsf[wv * 64 + fm * 16 + (lane >> 4) * 4 + r] = psum[fm][r];
    }
    __syncthreads();
    float sv = 0.f;
    if (tid < 64)
        sv = nsf[tid] + nsf[64 + tid] + nsf[128 + tid] + nsf[192 + tid];
    // pass 1: hi halves
#pragma unroll
    for (int fm = 0; fm < 4; ++fm)
#pragma unroll
        for (int fn = 0; fn < 4; ++fn)
#pragma unroll
            for (int r = 0; r < 4; ++r) {
                float v = acc[fm][fn][r];
                float hf = __uint_as_float(__float_as_uint(v) & 0xFFFFE000u);
                int pix_l = fm * 16 + (lane >> 4) * 4 + r;
                int chan_l = wv * 64 + fn * 16 + frow;
                yb[pix_l * 264 + chan_l] = (_Float16)hf;
            }
    __syncthreads();
    {
        int row = tid >> 2, seg = tid & 3;
        _Float16* gp = yh + ((size_t)img * HW + n0 + row) * CCHNK + cb * 256 + seg * 64;
#pragma unroll
        for (int i = 0; i < 8; ++i)
            *(half8*)(gp + i * 8) = *(const half8*)(yb + row * 264 + seg * 64 + i * 8);
    }
    __syncthreads();
    // pass 2: lo halves
#pragma unroll
    for (int fm = 0; fm < 4; ++fm)
#pragma unroll
        for (int fn = 0; fn < 4; ++fn)
#pragma unroll
            for (int r = 0; r < 4; ++r) {
                float v = acc[fm][fn][r];
                float hf = __uint_as_float(__float_as_uint(v) & 0xFFFFE000u);
                int pix_l = fm * 16 + (lane >> 4) * 4 + r;
                int chan_l = wv * 64 + fn * 16 + frow;
                yb[pix_l * 264 + chan_l] = (_Float16)(v - hf);
            }
    __syncthreads();
    {
        int row = tid >> 2, seg = tid & 3;
        _Float16* gp = yl + ((size_t)img * HW + n0 + row) * CCHNK + cb * 256 + seg * 64;
#pragma unroll
        for (int i = 0; i < 8; ++i)
            *(half8*)(gp + i * 8) = *(const half8*)(yb + row * 264 + seg * 64 + i * 8);
    }
    if (tid < 64) {
        float* np = nrm_parts + ((size_t)img * 2 + cb) * HW + n0 + tid;
        if (FIRST) *np = sv; else *np += sv;
    }
}

// ---------------------------------------------------------------------------
// Kernel 4: correlation via MFMA — LDS-FREE, BARRIER-FREE main loop.
// Fragments load directly from planar-f16 ychunk (register layout matches
// global layout). Block 256 thr = 4 waves 2x2; tile 128t x 128s; wave 64x64.
// MODE 0: store; 1: accumulate; 2: accumulate+normalize+max partials.
// grid (8 sb, 8 tb, 4 b), 256 thr.
// ---------------------------------------------------------------------------
template <int MODE>
__global__ __launch_bounds__(256) void corr_mfma(
    const _Float16* __restrict__ yh, const _Float16* __restrict__ yl,
    const float* __restrict__ nrm_sq, float* __restrict__ corrT,
    float* __restrict__ spar, float* __restrict__ tpar) {
    __shared__ float rm[2][128];
    __shared__ float cm[2][128];
    int sb = blockIdx.x, tb = blockIdx.y, b = blockIdx.z;
    int tid = threadIdx.x, lane = tid & 63, wv = tid >> 6;
    int wm = wv >> 1, wn = wv & 1;
    int frow = lane & 15, kg = (lane >> 4) * 8;

    size_t trow = (size_t)(4 + b) * HW + tb * 128 + wm * 64 + frow;
    size_t srow = (size_t)b * HW + sb * 128 + wn * 64 + frow;
    const _Float16* ahp = yh + trow * CCHNK + kg;
    const _Float16* alp = yl + trow * CCHNK + kg;
    const _Float16* bhp = yh + srow * CCHNK + kg;
    const _Float16* blp = yl + srow * CCHNK + kg;

    f32x4 acc[4][4] = {};
#pragma unroll 2
    for (int t = 0; t < 16; ++t) {
        int k0 = t * 32;
        half8 ah[4], al_[4], bh[4], bl[4];
#pragma unroll
        for (int f = 0; f < 4; ++f) {
            size_t ro = (size_t)f * 16 * CCHNK + k0;
            ah[f]  = *(const half8*)(ahp + ro);
            al_[f] = *(const half8*)(alp + ro);
            bh[f]  = *(const half8*)(bhp + ro);
            bl[f]  = *(const half8*)(blp + ro);
        }
#pragma unroll
        for (int fm = 0; fm < 4; ++fm)
#pragma unroll
            for (int fn = 0; fn < 4; ++fn) {
                acc[fm][fn] = __builtin_amdgcn_mfma_f32_16x16x32_f16(ah[fm],  bh[fn], acc[fm][fn], 0, 0, 0);
                acc[fm][fn] = __builtin_amdgcn_mfma_f32_16x16x32_f16(ah[fm],  bl[fn], acc[fm][fn], 0, 0, 0);
                acc[fm][fn] = __builtin_amdgcn_mfma_f32_16x16x32_f16(al_[fm], bh[fn], acc[fm][fn], 0, 0, 0);
            }
    }

    float rnt[4][4], rns[4];
    float rowmax[4][4] = {};
    float colmax[4] = {};
    if (MODE == 2) {
#pragma unroll
        for (int fm = 0; fm < 4; ++fm)
#pragma unroll
            for (int r = 0; r < 4; ++r) {
                int t = tb * 128 + wm * 64 + fm * 16 + (lane >> 4) * 4 + r;
                rnt[fm][r] = 1.f / sqrtf(nrm_sq[(size_t)(4 + b) * HW + t] + 1e-6f);
            }
#pragma unroll
        for (int fn = 0; fn < 4; ++fn) {
            int s_ = sb * 128 + wn * 64 + fn * 16 + frow;
            rns[fn] = 1.f / sqrtf(nrm_sq[(size_t)b * HW + s_] + 1e-6f);
        }
    }
#pragma unroll
    for (int fm = 0; fm < 4; ++fm)
#pragma unroll
        for (int r = 0; r < 4; ++r) {
            int t = tb * 128 + wm * 64 + fm * 16 + (lane >> 4) * 4 + r;
            float* cp = corrT + ((size_t)b * HW + t) * HW + sb * 128 + wn * 64 + frow;
#pragma unroll
            for (int fn = 0; fn < 4; ++fn) {
                float v = acc[fm][fn][r];
                if (MODE >= 1) v += cp[fn * 16];
                if (MODE == 2) {
                    v *= rnt[fm][r] * rns[fn];
                    rowmax[fm][r] = fmaxf(rowmax[fm][r], v);
                    colmax[fn] = fmaxf(colmax[fn], v);
                }
                cp[fn * 16] = v;
            }
        }
    if (MODE == 2) {
#pragma unroll
        for (int off = 1; off <= 8; off <<= 1)
#pragma unroll
            for (int fm = 0; fm < 4; ++fm)
#pragma unroll
                for (int r = 0; r < 4; ++r)
                    rowmax[fm][r] = fmaxf(rowmax[fm][r], __shfl_xor(rowmax[fm][r], off));
        if (frow == 0) {
#pragma unroll
            for (int fm = 0; fm < 4; ++fm)
#pragma unroll
                for (int r = 0; r < 4; ++r)
                    rm[wn][wm * 64 + fm * 16 + (lane >> 4) * 4 + r] = rowmax[fm][r];
        }
#pragma unroll
        for (int off = 16; off <= 32; off <<= 1)
#pragma unroll
            for (int fn = 0; fn < 4; ++fn)
                colmax[fn] = fmaxf(colmax[fn], __shfl_xor(colmax[fn], off));
        if (lane < 16) {
#pragma unroll
            for (int fn = 0; fn < 4; ++fn)
                cm[wm][wn * 64 + fn * 16 + lane] = colmax[fn];
        }
        __syncthreads();
        if (tid < 128)
            tpar[((size_t)b * 8 + sb) * HW + tb * 128 + tid] = fmaxf(rm[0][tid], rm[1][tid]);
        if (tid < 128)
            spar[((size_t)b * 8 + tb) * HW + sb * 128 + tid] = fmaxf(cm[0][tid], cm[1][tid]);
    }
}

// ---------------------------------------------------------------------------
// Kernel 5: nrm_sq = sum of 2 chan-block partials
// ---------------------------------------------------------------------------
__global__ void nrm_reduce(const float* __restrict__ nrm_parts, float* __restrict__ nrm_sq) {
    int img = blockIdx.y;
    int p = blockIdx.x * 256 + threadIdx.x;
    nrm_sq[img * HW + p] = nrm_parts[((size_t)img * 2 + 0) * HW + p]
                         + nrm_parts[((size_t)img * 2 + 1) * HW + p];
}

// ---------------------------------------------------------------------------
// Kernel 6: combine smax / tmax partials (8 each)
// ---------------------------------------------------------------------------
__global__ void combine_max(const float* __restrict__ spar, const float* __restrict__ tpar,
                            float* __restrict__ smax, float* __restrict__ tmax) {
    int b = blockIdx.y;
    int i = blockIdx.x * 256 + threadIdx.x;
    float m = 0.f;
#pragma unroll
    for (int q = 0; q < 8; ++q) m = fmaxf(m, spar[((size_t)b * 8 + q) * HW + i]);
    smax[b * HW + i] = m;
    float m2 = 0.f;
#pragma unroll
    for (int q = 0; q < 8; ++q) m2 = fmaxf(m2, tpar[((size_t)b * 8 + q) * HW + i]);
    tmax[b * HW + i] = m2;
}

// ---------------------------------------------------------------------------
// Kernel 7: final — filter per tap row, separable bilinear, softmax-argmax.
// ---------------------------------------------------------------------------
__global__ __launch_bounds__(256) void final_kernel(const float* __restrict__ corrT,
                                                    const float* __restrict__ smax,
                                                    const float* __restrict__ tmax,
                                                    float* __restrict__ out) {
    __shared__ float vsh[1024];
    __shared__ float rbuf[16];
    int b = blockIdx.z;
    int typ = blockIdx.y;
    int txp = blockIdx.x;
    int tid = threadIdx.x;

    float fy = typ * (31.0f / 63.0f);
    int y0 = min((int)fy, 31); int y1 = min(y0 + 1, 31);
    float wy = fy - (float)y0;
    float fx = txp * (31.0f / 63.0f);
    int x0 = min((int)fx, 31); int x1 = min(x0 + 1, 31);
    float wx = fx - (float)x0;
    int tA = y0 * 32 + x0, tB = y0 * 32 + x1, tC = y1 * 32 + x0, tD = y1 * 32 + x1;
    const float* base = corrT + (size_t)b * HW * HW;
    const float* rA = base + (size_t)tA * HW;
    const float* rB = base + (size_t)tB * HW;
    const float* rC = base + (size_t)tC * HW;
    const float* rD = base + (size_t)tD * HW;
    float tmA_ = tmax[b * HW + tA]; if (tmA_ == 0.f) tmA_ = 1e-30f;
    float tmB_ = tmax[b * HW + tB]; if (tmB_ == 0.f) tmB_ = 1e-30f;
    float tmC_ = tmax[b * HW + tC]; if (tmC_ == 0.f) tmC_ = 1e-30f;
    float tmD_ = tmax[b * HW + tD]; if (tmD_ == 0.f) tmD_ = 1e-30f;
    float itA = 1.f / tmA_, itB = 1.f / tmB_, itC = 1.f / tmC_, itD = 1.f / tmD_;
    float wA = (1.f - wy) * (1.f - wx), wB = (1.f - wy) * wx;
    float wC = wy * (1.f - wx), wD = wy * wx;
#pragma unroll
    for (int u = 0; u < 4; ++u) {
        int s = u * 256 + tid;
        float sm = smax[b * HW + s]; if (sm == 0.f) sm = 1e-30f;
        float is = 1.f / sm;
        float a = rA[s]; a = a * a * a * is * itA;
        float b2 = rB[s]; b2 = b2 * b2 * b2 * is * itB;
        float c2 = rC[s]; c2 = c2 * c2 * c2 * is * itC;
        float d2 = rD[s]; d2 = d2 * d2 * d2 * is * itD;
        vsh[s] = wA * a + wB * b2 + wC * c2 + wD * d2;
    }
    __syncthreads();

    int jx = tid & 63;
    int wvq = tid >> 6;
    float gxx = jx * (31.0f / 63.0f);
    int sx0 = min((int)gxx, 31), sx1 = min(sx0 + 1, 31);
    float wxx = gxx - (float)sx0, iwxx = 1.f - wxx;
    float xnj = jx * (2.0f / 63.0f) - 1.0f;

    float cv[16];
    float lmax = -1e30f;
#pragma unroll
    for (int u = 0; u < 16; ++u) {
        int iy = u * 4 + wvq;
        float gy = iy * (31.0f / 63.0f);
        int sy0 = min((int)gy, 31), sy1 = min(sy0 + 1, 31);
        float wyy = gy - (float)sy0;
        float r0 = vsh[sy0 * 32 + sx0] * iwxx + vsh[sy0 * 32 + sx1] * wxx;
        float r1 = vsh[sy1 * 32 + sx0] * iwxx + vsh[sy1 * 32 + sx1] * wxx;
        cv[u] = (r0 * (1.f - wyy) + r1 * wyy) * 50.0f;
        lmax = fmaxf(lmax, cv[u]);
    }
#pragma unroll
    for (int off = 32; off >= 1; off >>= 1) lmax = fmaxf(lmax, __shfl_down(lmax, off));
    int lane = tid & 63;
    if (lane == 0) rbuf[wvq] = lmax;
    __syncthreads();
    if (tid == 0) {
        float m = rbuf[0];
        for (int i = 1; i < 4; ++i) m = fmaxf(m, rbuf[i]);
        rbuf[0] = m;
    }
    __syncthreads();
    float m = rbuf[0];

    float e0 = 0.f, ex = 0.f, ey = 0.f;
#pragma unroll
    for (int u = 0; u < 16; ++u) {
        int iy = u * 4 + wvq;
        float e = __expf(cv[u] - m);
        e0 += e;
        ex = fmaf(e, xnj, ex);
        ey = fmaf(e, iy * (2.0f / 63.0f) - 1.0f, ey);
    }
#pragma unroll
    for (int off = 32; off >= 1; off >>= 1) {
        e0 += __shfl_down(e0, off);
        ex += __shfl_down(ex, off);
        ey += __shfl_down(ey, off);
    }
    if (lane == 0) { rbuf[4 + wvq] = e0; rbuf[8 + wvq] = ex; rbuf[12 + wvq] = ey; }
    __syncthreads();
    if (tid == 0) {
        float s0 = rbuf[4] + rbuf[5] + rbuf[6] + rbuf[7];
        float sx = rbuf[8] + rbuf[9] + rbuf[10] + rbuf[11];
        float sy = rbuf[12] + rbuf[13] + rbuf[14] + rbuf[15];
        float gx = sx / s0, gy = sy / s0;
        float mx = (gx + 1.f) * 31.5f;
        float my = (gy + 1.f) * 31.5f;
        out[(((size_t)b * 2 + 0) * 64 + typ) * 64 + txp] = mx - (float)txp;
        out[(((size_t)b * 2 + 1) * 64 + typ) * 64 + txp] = my - (float)typ;
    }
}

// ---------------------------------------------------------------------------
// Workspace (float units), total 8,724,480 = 33.28 MiB (< proven 33.47):
//   corrT 4,194,304 | yh 2,097,152 | yl 2,097,152 | nrm_parts 16,384
//   tpar 32,768 | nrm_sq 8,192 | smax 4,096 | spar 32,768 | tmax 4,096
//   pnorm 8,192 | ctxbuf 229,376.  pparts aliases yh (dead before conv).
// ---------------------------------------------------------------------------
extern "C" void kernel_launch(void* const* d_in, const int* in_sizes, int n_in,
                              void* d_out, int out_size, void* d_ws, size_t ws_size,
                              hipStream_t stream) {
    const float* src  = (const float*)d_in[0];
    const float* tgt  = (const float*)d_in[1];
    const float* sw   = (const float*)d_in[2];
    const float* sb   = (const float*)d_in[3];
    float* out = (float*)d_out;

    float* f = (float*)d_ws;
    float*     corrT     = f;
    _Float16*  yh        = (_Float16*)(f + 4194304);
    _Float16*  yl        = (_Float16*)(f + 4194304 + 2097152);
    float*     nrm_parts = f + 8388608;
    float*     tpar      = nrm_parts + 16384;
    float*     nrm_sq    = tpar + 32768;
    float*     smax      = nrm_sq + 8192;
    float*     spar      = smax + 4096;
    float*     tmax      = spar + 32768;
    float*     pnorm     = tmax + 4096;
    float*     ctxbuf    = pnorm + 8192;
    float*     pparts    = (float*)yh;     // alias, dead before conv chunk 0

    pnorm_part<<<dim3(8, 16, 4), 64, 0, stream>>>(src, tgt, pparts);
    pnorm_combine<<<dim3(8, 16), 64, 0, stream>>>(pparts, pnorm);
    ctx_kernel<<<dim3(8, 32), 896, 0, stream>>>(src, tgt, pnorm, ctxbuf);

    conv_mfma<true><<<dim3(2, 16, 8), 256, 0, stream>>>(src, tgt, ctxbuf, sw, sb,
                                                        yh, yl, nrm_parts, 0);
    corr_mfma<0><<<dim3(8, 8, 4), 256, 0, stream>>>(yh, yl, nrm_sq, corrT, spar, tpar);
    for (int c = 1; c < 3; ++c) {
        conv_mfma<false><<<dim3(2, 16, 8), 256, 0, stream>>>(src, tgt, ctxbuf, sw, sb,
                                                             yh, yl, nrm_parts, c * CCHNK);
        corr_mfma<1><<<dim3(8, 8, 4), 256, 0, stream>>>(yh, yl, nrm_sq, corrT, spar, tpar);
    }
    conv_mfma<false><<<dim3(2, 16, 8), 256, 0, stream>>>(src, tgt, ctxbuf, sw, sb,
                                                         yh, yl, nrm_parts, 3 * CCHNK);
    nrm_reduce<<<dim3(4, 8), 256, 0, stream>>>(nrm_parts, nrm_sq);
    corr_mfma<2><<<dim3(8, 8, 4), 256, 0, stream>>>(yh, yl, nrm_sq, corrT, spar, tpar);

    combine_max<<<dim3(4, 4), 256, 0, stream>>>(spar, tpar, smax, tmax);
    final_kernel<<<dim3(64, 64, 4), 256, 0, stream>>>(corrT, smax, tmax, out);
}

// Round 10
// 608.186 us; speedup vs baseline: 1.0416x; 1.0416x over previous
//
#include <hip/hip_runtime.h>
#include <math.h>

#define HW    1024
#define CIN   1024
#define CCTX  28
#define CALL  1052
#define COUT  2048
#define CCHNK 512

typedef _Float16 half8   __attribute__((ext_vector_type(8)));
typedef _Float16 half4_t __attribute__((ext_vector_type(4)));
typedef _Float16 half2_t __attribute__((ext_vector_type(2)));
typedef __fp16   fp16x2  __attribute__((ext_vector_type(2)));
typedef float    f32x4   __attribute__((ext_vector_type(4)));

// split a into hi (top-10-bit mantissa, exact in f16) + lo, packed pairwise.
__device__ __forceinline__ void split2(float a0, float a1, half2_t& h, half2_t& l) {
    float h0 = __uint_as_float(__float_as_uint(a0) & 0xFFFFE000u);
    float h1 = __uint_as_float(__float_as_uint(a1) & 0xFFFFE000u);
    fp16x2 hp = __builtin_amdgcn_cvt_pkrtz(h0, h1);
    fp16x2 lp = __builtin_amdgcn_cvt_pkrtz(a0 - h0, a1 - h1);
    h = __builtin_bit_cast(half2_t, hp);
    l = __builtin_bit_cast(half2_t, lp);
}
__device__ __forceinline__ void split4(float4 v, half4_t& h, half4_t& l) {
    half2_t ha, la, hb, lb;
    split2(v.x, v.y, ha, la);
    split2(v.z, v.w, hb, lb);
    h = __builtin_shufflevector(ha, hb, 0, 1, 2, 3);
    l = __builtin_shufflevector(la, lb, 0, 1, 2, 3);
}
__device__ __forceinline__ float f4get(const float4& v, int e) {
    return e == 0 ? v.x : e == 1 ? v.y : e == 2 ? v.z : v.w;
}
// ctx offset table: o -> (r, c)
__device__ __forceinline__ void ctx_offset(int o, int& r, int& c) {
    int g = o / 7, i = o % 7;
    if (g == 0)      { r = i; c = i; }
    else if (g == 1) { r = i; c = 3; }
    else if (g == 2) { r = i; c = 6 - i; }
    else             { r = 3; c = i; }
}

// ---------------------------------------------------------------------------
// pnorm partials + combine (proven round-9 form)
// ---------------------------------------------------------------------------
__global__ void pnorm_part(const float* __restrict__ src, const float* __restrict__ tgt,
                           float* __restrict__ parts) {
    int img = blockIdx.x, pb = blockIdx.y, part = blockIdx.z;
    int p = pb * 64 + threadIdx.x;
    const float* feat = ((img < 4) ? src + (size_t)img * CIN * HW
                                   : tgt + (size_t)(img - 4) * CIN * HW)
                        + (size_t)part * 256 * HW + p;
    float a4[4] = {};
    for (int c = 0; c < 256; c += 8) {
        float v[8];
#pragma unroll
        for (int j = 0; j < 8; ++j) v[j] = feat[(size_t)(c + j) * HW];
#pragma unroll
        for (int j = 0; j < 8; ++j) a4[j & 3] = fmaf(v[j], v[j], a4[j & 3]);
    }
    parts[(size_t)part * 8192 + img * 1024 + p] = (a4[0] + a4[1]) + (a4[2] + a4[3]);
}
__global__ void pnorm_combine(const float* __restrict__ parts, float* __restrict__ pnorm) {
    int img = blockIdx.x;
    int p = blockIdx.y * 64 + threadIdx.x;
    float s = parts[img * 1024 + p] + parts[8192 + img * 1024 + p]
            + parts[16384 + img * 1024 + p] + parts[24576 + img * 1024 + p];
    pnorm[img * HW + p] = fmaxf(sqrtf(s), 1e-12f);
}

// ---------------------------------------------------------------------------
// ctx split into 8 channel-parts (occupancy) + combine with norms.
// ctxpar[part][img][o][p]; OOB -> 0 so combine needs no branch.
// ---------------------------------------------------------------------------
__global__ void ctx_part(const float* __restrict__ src, const float* __restrict__ tgt,
                         float* __restrict__ ctxpar) {
    int img = blockIdx.x, y = blockIdx.y, part = blockIdx.z;
    int tid = threadIdx.x;
    int o = tid >> 5, x = tid & 31;
    const float* feat = ((img < 4) ? src + (size_t)img * CIN * HW
                                   : tgt + (size_t)(img - 4) * CIN * HW)
                        + (size_t)part * 128 * HW;
    int r, c; ctx_offset(o, r, c);
    int y2 = y + r - 3, x2 = x + c - 3;
    int p = y * 32 + x;
    float acc = 0.f;
    if (y2 >= 0 && y2 < 32 && x2 >= 0 && x2 < 32) {
        int p2 = y2 * 32 + x2;
        const float* f0 = feat + p;
        const float* f1 = feat + p2;
        for (int ch = 0; ch < 128; ++ch)
            acc = fmaf(f0[(size_t)ch * HW], f1[(size_t)ch * HW], acc);
    }
    ctxpar[((size_t)part * 8 + img) * 28672 + o * 1024 + p] = acc;
}
__global__ void ctx_combine(const float* __restrict__ ctxpar, const float* __restrict__ pnorm,
                            float* __restrict__ ctxbuf) {
    int o = blockIdx.y, img = blockIdx.z;
    int p = blockIdx.x * 256 + threadIdx.x;
    float s = 0.f;
#pragma unroll
    for (int part = 0; part < 8; ++part)
        s += ctxpar[((size_t)part * 8 + img) * 28672 + o * 1024 + p];
    int r, c; ctx_offset(o, r, c);
    int y = p >> 5, x = p & 31;
    int y2 = y + r - 3, x2 = x + c - 3;
    bool inb = (y2 >= 0 && y2 < 32 && x2 >= 0 && x2 < 32);
    int p2 = inb ? y2 * 32 + x2 : p;
    float outv = s / (pnorm[img * HW + p] * pnorm[img * HW + p2]);
    ctxbuf[((size_t)img * CCTX + o) * 1024 + p] = outv;
}

// ---------------------------------------------------------------------------
// conv via MFMA. Block 256 thr = 4 waves; tile 64 pix x 128 chan
// (wave = 64 pix x 32 chan). Phase-major conflict-free LDS [kp][row][8],
// double-buffered (48 KB), 1 barrier/tile. Output planar f16 hi/lo
// ychunk [img][pix][512].  grid (4 cb, 16 pb, 8 img) = 512 blocks.
// ---------------------------------------------------------------------------
template <bool FIRST>
__global__ __launch_bounds__(256, 2) void conv_mfma(
    const float* __restrict__ src, const float* __restrict__ tgt,
    const float* __restrict__ ctxb, const float* __restrict__ w,
    const float* __restrict__ bias, _Float16* __restrict__ yh,
    _Float16* __restrict__ yl, float* __restrict__ nrm_parts, int c0) {
    // per buffer: Xh 2048 | Xl 2048 | Wh 4096 | Wl 4096  (halves)
    __shared__ __align__(16) _Float16 lds[2 * 12288];   // 49152 B

    int cb = blockIdx.x, pb = blockIdx.y, img = blockIdx.z;
    int n0 = pb * 64;
    int m0g = c0 + cb * 128;
    const float* feat = (img < 4) ? src + (size_t)img * CIN * HW
                                  : tgt + (size_t)(img - 4) * CIN * HW;
    const float* ctxi = ctxb + (size_t)img * CCTX * HW;
    int tid = threadIdx.x;
    int lane = tid & 63, wv = tid >> 6;
    int frow = lane & 15, kp = lane >> 4;
    int aq = tid & 15, ar = tid >> 4;        // X stage: pix-quad, k-pair
    int wrow = tid >> 1, wh_ = tid & 1;      // W stage: chan row, k-half

    float4 xa[2], xw[4];
    auto stage_regs = [&](int k0) {
#pragma unroll
        for (int j = 0; j < 2; ++j) {
            int k = k0 + ar * 2 + j;
            if (k < CIN)       xa[j] = *(const float4*)(feat + (size_t)k * HW + n0 + aq * 4);
            else if (k < CALL) xa[j] = *(const float4*)(ctxi + (size_t)(k - CIN) * HW + n0 + aq * 4);
            else               xa[j] = make_float4(0.f, 0.f, 0.f, 0.f);
        }
#pragma unroll
        for (int i = 0; i < 4; ++i) {
            int k = k0 + wh_ * 16 + i * 4;
            xw[i] = (k + 4 <= CALL) ? *(const float4*)(w + (size_t)(m0g + wrow) * CALL + k)
                                    : make_float4(0.f, 0.f, 0.f, 0.f);
        }
    };
    auto write_lds = [&](int buf) {
        _Float16* B = lds + buf * 12288;
        int xkp = ar >> 2, xoff = (ar & 3) * 2;
#pragma unroll
        for (int p = 0; p < 4; ++p) {
            half2_t h, l;
            split2(f4get(xa[0], p), f4get(xa[1], p), h, l);
            int idx = xkp * 512 + (aq * 4 + p) * 8 + xoff;
            *(half2_t*)(B + idx) = h;
            *(half2_t*)(B + 2048 + idx) = l;
        }
#pragma unroll
        for (int i2 = 0; i2 < 2; ++i2) {
            half4_t h0, l0, h1, l1;
            split4(xw[2 * i2], h0, l0);
            split4(xw[2 * i2 + 1], h1, l1);
            half8 hh = __builtin_shufflevector(h0, h1, 0, 1, 2, 3, 4, 5, 6, 7);
            half8 ll = __builtin_shufflevector(l0, l1, 0, 1, 2, 3, 4, 5, 6, 7);
            int idx = (wh_ * 2 + i2) * 1024 + wrow * 8;
            *(half8*)(B + 4096 + idx) = hh;
            *(half8*)(B + 8192 + idx) = ll;
        }
    };

    f32x4 acc[4][2] = {};
    const int NT = 33;
    stage_regs(0); write_lds(0);
    __syncthreads();
    for (int t = 0; t < NT; ++t) {
        const _Float16* Bc = lds + (t & 1) * 12288;
        half8 afh[4], afl[4], bfh[2], bfl[2];
#pragma unroll
        for (int fm = 0; fm < 4; ++fm) {
            int idx = kp * 512 + (fm * 16 + frow) * 8;
            afh[fm] = *(const half8*)(Bc + idx);
            afl[fm] = *(const half8*)(Bc + 2048 + idx);
        }
#pragma unroll
        for (int fn = 0; fn < 2; ++fn) {
            int idx = kp * 1024 + (wv * 32 + fn * 16 + frow) * 8;
            bfh[fn] = *(const half8*)(Bc + 4096 + idx);
            bfl[fn] = *(const half8*)(Bc + 8192 + idx);
        }
        if (t + 1 < NT) stage_regs((t + 1) * 32);
#pragma unroll
        for (int fm = 0; fm < 4; ++fm)
#pragma unroll
            for (int fn = 0; fn < 2; ++fn) {
                acc[fm][fn] = __builtin_amdgcn_mfma_f32_16x16x32_f16(afh[fm], bfh[fn], acc[fm][fn], 0, 0, 0);
                acc[fm][fn] = __builtin_amdgcn_mfma_f32_16x16x32_f16(afh[fm], bfl[fn], acc[fm][fn], 0, 0, 0);
                acc[fm][fn] = __builtin_amdgcn_mfma_f32_16x16x32_f16(afl[fm], bfh[fn], acc[fm][fn], 0, 0, 0);
            }
        if (t + 1 < NT) write_lds((t + 1) & 1);
        __syncthreads();
    }

    // epilogue: bias+relu, nrm partials, planar hi/lo bounce store
    float bv[2];
#pragma unroll
    for (int fn = 0; fn < 2; ++fn) bv[fn] = bias[m0g + wv * 32 + fn * 16 + frow];

    float* nsf = (float*)lds;                       // [4][64]
    _Float16* yb = lds + 512;                       // [64][136]
    float psum[4][4] = {};
#pragma unroll
    for (int fm = 0; fm < 4; ++fm)
#pragma unroll
        for (int fn = 0; fn < 2; ++fn)
#pragma unroll
            for (int r = 0; r < 4; ++r) {
                float v = fmaxf(acc[fm][fn][r] + bv[fn], 0.f);
                acc[fm][fn][r] = v;
                psum[fm][r] = fmaf(v, v, psum[fm][r]);
            }
#pragma unroll
    for (int off = 1; off <= 8; off <<= 1)
#pragma unroll
        for (int fm = 0; fm < 4; ++fm)
#pragma unroll
            for (int r = 0; r < 4; ++r)
                psum[fm][r] = psum[fm][r] + __shfl_xor(psum[fm][r], off);
    if (frow == 0) {
#pragma unroll
        for (int fm = 0; fm < 4; ++fm)
#pragma unroll
            for (int r = 0; r < 4; ++r)
                nsf[wv * 64 + fm * 16 + kp * 4 + r] = psum[fm][r];
    }
    __syncthreads();
    float sv = 0.f;
    if (tid < 64)
        sv = nsf[tid] + nsf[64 + tid] + nsf[128 + tid] + nsf[192 + tid];
    __syncthreads();
    // pass 1: hi
#pragma unroll
    for (int fm = 0; fm < 4; ++fm)
#pragma unroll
        for (int fn = 0; fn < 2; ++fn)
#pragma unroll
            for (int r = 0; r < 4; ++r) {
                float v = acc[fm][fn][r];
                float hf = __uint_as_float(__float_as_uint(v) & 0xFFFFE000u);
                int pix_l = fm * 16 + kp * 4 + r;
                int chan_l = wv * 32 + fn * 16 + frow;
                yb[pix_l * 136 + chan_l] = (_Float16)hf;
            }
    __syncthreads();
    {
        int row = tid >> 2, seg = tid & 3;
        _Float16* gp = yh + ((size_t)img * HW + n0 + row) * CCHNK + cb * 128 + seg * 32;
#pragma unroll
        for (int i = 0; i < 4; ++i)
            *(half8*)(gp + i * 8) = *(const half8*)(yb + row * 136 + seg * 32 + i * 8);
    }
    __syncthreads();
    // pass 2: lo
#pragma unroll
    for (int fm = 0; fm < 4; ++fm)
#pragma unroll
        for (int fn = 0; fn < 2; ++fn)
#pragma unroll
            for (int r = 0; r < 4; ++r) {
                float v = acc[fm][fn][r];
                float hf = __uint_as_float(__float_as_uint(v) & 0xFFFFE000u);
                int pix_l = fm * 16 + kp * 4 + r;
                int chan_l = wv * 32 + fn * 16 + frow;
                yb[pix_l * 136 + chan_l] = (_Float16)(v - hf);
            }
    __syncthreads();
    {
        int row = tid >> 2, seg = tid & 3;
        _Float16* gp = yl + ((size_t)img * HW + n0 + row) * CCHNK + cb * 128 + seg * 32;
#pragma unroll
        for (int i = 0; i < 4; ++i)
            *(half8*)(gp + i * 8) = *(const half8*)(yb + row * 136 + seg * 32 + i * 8);
    }
    if (tid < 64) {
        float* np = nrm_parts + ((size_t)img * 4 + cb) * HW + n0 + tid;
        if (FIRST) *np = sv; else *np += sv;
    }
}

// ---------------------------------------------------------------------------
// corr via MFMA — 1-wave blocks, LDS-free, barrier-free. Wave tile 64t x 32s.
// grid (32 sb, 16 tb, 4 b) = 2048 blocks -> 8 waves/CU.
// MODE 0: store; 1: accumulate; 2: accumulate+normalize+max partials.
// ---------------------------------------------------------------------------
template <int MODE>
__global__ __launch_bounds__(64) void corr_mfma(
    const _Float16* __restrict__ yh, const _Float16* __restrict__ yl,
    const float* __restrict__ nrm_sq, float* __restrict__ corrT,
    float* __restrict__ spar, float* __restrict__ tpar) {
    int sb = blockIdx.x, tb = blockIdx.y, b = blockIdx.z;
    int lane = threadIdx.x;
    int frow = lane & 15, kp = lane >> 4;

    size_t trow = (size_t)(4 + b) * HW + tb * 64 + frow;
    size_t srow = (size_t)b * HW + sb * 32 + frow;
    const _Float16* ahp = yh + trow * CCHNK + kp * 8;
    const _Float16* alp = yl + trow * CCHNK + kp * 8;
    const _Float16* bhp = yh + srow * CCHNK + kp * 8;
    const _Float16* blp = yl + srow * CCHNK + kp * 8;

    f32x4 acc[4][2] = {};
#pragma unroll 4
    for (int t = 0; t < 16; ++t) {
        int k0 = t * 32;
        half8 ah[4], al_[4], bh[2], bl[2];
#pragma unroll
        for (int fm = 0; fm < 4; ++fm) {
            size_t ro = (size_t)fm * 16 * CCHNK + k0;
            ah[fm]  = *(const half8*)(ahp + ro);
            al_[fm] = *(const half8*)(alp + ro);
        }
#pragma unroll
        for (int fn = 0; fn < 2; ++fn) {
            size_t ro = (size_t)fn * 16 * CCHNK + k0;
            bh[fn] = *(const half8*)(bhp + ro);
            bl[fn] = *(const half8*)(blp + ro);
        }
#pragma unroll
        for (int fm = 0; fm < 4; ++fm)
#pragma unroll
            for (int fn = 0; fn < 2; ++fn) {
                acc[fm][fn] = __builtin_amdgcn_mfma_f32_16x16x32_f16(ah[fm],  bh[fn], acc[fm][fn], 0, 0, 0);
                acc[fm][fn] = __builtin_amdgcn_mfma_f32_16x16x32_f16(ah[fm],  bl[fn], acc[fm][fn], 0, 0, 0);
                acc[fm][fn] = __builtin_amdgcn_mfma_f32_16x16x32_f16(al_[fm], bh[fn], acc[fm][fn], 0, 0, 0);
            }
    }

    float rnt[4][4], rns[2];
    float rowmax[4][4] = {};
    float colmax[2] = {0.f, 0.f};
    if (MODE == 2) {
#pragma unroll
        for (int fm = 0; fm < 4; ++fm)
#pragma unroll
            for (int r = 0; r < 4; ++r) {
                int t = tb * 64 + fm * 16 + kp * 4 + r;
                rnt[fm][r] = 1.f / sqrtf(nrm_sq[(size_t)(4 + b) * HW + t] + 1e-6f);
            }
#pragma unroll
        for (int fn = 0; fn < 2; ++fn) {
            int s_ = sb * 32 + fn * 16 + frow;
            rns[fn] = 1.f / sqrtf(nrm_sq[(size_t)b * HW + s_] + 1e-6f);
        }
    }
#pragma unroll
    for (int fm = 0; fm < 4; ++fm)
#pragma unroll
        for (int r = 0; r < 4; ++r) {
            int t = tb * 64 + fm * 16 + kp * 4 + r;
            float* cp = corrT + ((size_t)b * HW + t) * HW + sb * 32 + frow;
#pragma unroll
            for (int fn = 0; fn < 2; ++fn) {
                float v = acc[fm][fn][r];
                if (MODE >= 1) v += cp[fn * 16];
                if (MODE == 2) {
                    v *= rnt[fm][r] * rns[fn];
                    rowmax[fm][r] = fmaxf(rowmax[fm][r], v);
                    colmax[fn] = fmaxf(colmax[fn], v);
                }
                cp[fn * 16] = v;
            }
        }
    if (MODE == 2) {
        // tmax partials: reduce over s (frow lanes)
#pragma unroll
        for (int off = 1; off <= 8; off <<= 1)
#pragma unroll
            for (int fm = 0; fm < 4; ++fm)
#pragma unroll
                for (int r = 0; r < 4; ++r)
                    rowmax[fm][r] = fmaxf(rowmax[fm][r], __shfl_xor(rowmax[fm][r], off));
        if (frow == 0) {
#pragma unroll
            for (int fm = 0; fm < 4; ++fm)
#pragma unroll
                for (int r = 0; r < 4; ++r)
                    tpar[((size_t)b * 32 + sb) * HW + tb * 64 + fm * 16 + kp * 4 + r] = rowmax[fm][r];
        }
        // smax partials: reduce over t (kp groups)
#pragma unroll
        for (int off = 16; off <= 32; off <<= 1)
#pragma unroll
            for (int fn = 0; fn < 2; ++fn)
                colmax[fn] = fmaxf(colmax[fn], __shfl_xor(colmax[fn], off));
        if (kp == 0) {
#pragma unroll
            for (int fn = 0; fn < 2; ++fn)
                spar[((size_t)b * 16 + tb) * HW + sb * 32 + fn * 16 + lane] = colmax[fn];
        }
    }
}

// ---------------------------------------------------------------------------
// nrm_sq = sum of 4 chan-block partials
// ---------------------------------------------------------------------------
__global__ void nrm_reduce(const float* __restrict__ nrm_parts, float* __restrict__ nrm_sq) {
    int img = blockIdx.y;
    int p = blockIdx.x * 256 + threadIdx.x;
    float s = 0.f;
#pragma unroll
    for (int mb = 0; mb < 4; ++mb)
        s += nrm_parts[((size_t)img * 4 + mb) * HW + p];
    nrm_sq[img * HW + p] = s;
}

// ---------------------------------------------------------------------------
// combine smax (16 tb partials) / tmax (32 sb partials)
// ---------------------------------------------------------------------------
__global__ void combine_max(const float* __restrict__ spar, const float* __restrict__ tpar,
                            float* __restrict__ smax, float* __restrict__ tmax) {
    int b = blockIdx.y;
    int i = blockIdx.x * 256 + threadIdx.x;
    float m = 0.f;
#pragma unroll
    for (int q = 0; q < 16; ++q) m = fmaxf(m, spar[((size_t)b * 16 + q) * HW + i]);
    smax[b * HW + i] = m;
    float m2 = 0.f;
#pragma unroll
    for (int q = 0; q < 32; ++q) m2 = fmaxf(m2, tpar[((size_t)b * 32 + q) * HW + i]);
    tmax[b * HW + i] = m2;
}

// ---------------------------------------------------------------------------
// final — filter per tap row, separable bilinear, softmax-argmax (proven).
// ---------------------------------------------------------------------------
__global__ __launch_bounds__(256) void final_kernel(const float* __restrict__ corrT,
                                                    const float* __restrict__ smax,
                                                    const float* __restrict__ tmax,
                                                    float* __restrict__ out) {
    __shared__ float vsh[1024];
    __shared__ float rbuf[16];
    int b = blockIdx.z;
    int typ = blockIdx.y;
    int txp = blockIdx.x;
    int tid = threadIdx.x;

    float fy = typ * (31.0f / 63.0f);
    int y0 = min((int)fy, 31); int y1 = min(y0 + 1, 31);
    float wy = fy - (float)y0;
    float fx = txp * (31.0f / 63.0f);
    int x0 = min((int)fx, 31); int x1 = min(x0 + 1, 31);
    float wx = fx - (float)x0;
    int tA = y0 * 32 + x0, tB = y0 * 32 + x1, tC = y1 * 32 + x0, tD = y1 * 32 + x1;
    const float* base = corrT + (size_t)b * HW * HW;
    const float* rA = base + (size_t)tA * HW;
    const float* rB = base + (size_t)tB * HW;
    const float* rC = base + (size_t)tC * HW;
    const float* rD = base + (size_t)tD * HW;
    float tmA_ = tmax[b * HW + tA]; if (tmA_ == 0.f) tmA_ = 1e-30f;
    float tmB_ = tmax[b * HW + tB]; if (tmB_ == 0.f) tmB_ = 1e-30f;
    float tmC_ = tmax[b * HW + tC]; if (tmC_ == 0.f) tmC_ = 1e-30f;
    float tmD_ = tmax[b * HW + tD]; if (tmD_ == 0.f) tmD_ = 1e-30f;
    float itA = 1.f / tmA_, itB = 1.f / tmB_, itC = 1.f / tmC_, itD = 1.f / tmD_;
    float wA = (1.f - wy) * (1.f - wx), wB = (1.f - wy) * wx;
    float wC = wy * (1.f - wx), wD = wy * wx;
#pragma unroll
    for (int u = 0; u < 4; ++u) {
        int s = u * 256 + tid;
        float sm = smax[b * HW + s]; if (sm == 0.f) sm = 1e-30f;
        float is = 1.f / sm;
        float a = rA[s]; a = a * a * a * is * itA;
        float b2 = rB[s]; b2 = b2 * b2 * b2 * is * itB;
        float c2 = rC[s]; c2 = c2 * c2 * c2 * is * itC;
        float d2 = rD[s]; d2 = d2 * d2 * d2 * is * itD;
        vsh[s] = wA * a + wB * b2 + wC * c2 + wD * d2;
    }
    __syncthreads();

    int jx = tid & 63;
    int wvq = tid >> 6;
    float gxx = jx * (31.0f / 63.0f);
    int sx0 = min((int)gxx, 31), sx1 = min(sx0 + 1, 31);
    float wxx = gxx - (float)sx0, iwxx = 1.f - wxx;
    float xnj = jx * (2.0f / 63.0f) - 1.0f;

    float cv[16];
    float lmax = -1e30f;
#pragma unroll
    for (int u = 0; u < 16; ++u) {
        int iy = u * 4 + wvq;
        float gy = iy * (31.0f / 63.0f);
        int sy0 = min((int)gy, 31), sy1 = min(sy0 + 1, 31);
        float wyy = gy - (float)sy0;
        float r0 = vsh[sy0 * 32 + sx0] * iwxx + vsh[sy0 * 32 + sx1] * wxx;
        float r1 = vsh[sy1 * 32 + sx0] * iwxx + vsh[sy1 * 32 + sx1] * wxx;
        cv[u] = (r0 * (1.f - wyy) + r1 * wyy) * 50.0f;
        lmax = fmaxf(lmax, cv[u]);
    }
#pragma unroll
    for (int off = 32; off >= 1; off >>= 1) lmax = fmaxf(lmax, __shfl_down(lmax, off));
    int lane = tid & 63;
    if (lane == 0) rbuf[wvq] = lmax;
    __syncthreads();
    if (tid == 0) {
        float m = rbuf[0];
        for (int i = 1; i < 4; ++i) m = fmaxf(m, rbuf[i]);
        rbuf[0] = m;
    }
    __syncthreads();
    float m = rbuf[0];

    float e0 = 0.f, ex = 0.f, ey = 0.f;
#pragma unroll
    for (int u = 0; u < 16; ++u) {
        int iy = u * 4 + wvq;
        float e = __expf(cv[u] - m);
        e0 += e;
        ex = fmaf(e, xnj, ex);
        ey = fmaf(e, iy * (2.0f / 63.0f) - 1.0f, ey);
    }
#pragma unroll
    for (int off = 32; off >= 1; off >>= 1) {
        e0 += __shfl_down(e0, off);
        ex += __shfl_down(ex, off);
        ey += __shfl_down(ey, off);
    }
    if (lane == 0) { rbuf[4 + wvq] = e0; rbuf[8 + wvq] = ex; rbuf[12 + wvq] = ey; }
    __syncthreads();
    if (tid == 0) {
        float s0 = rbuf[4] + rbuf[5] + rbuf[6] + rbuf[7];
        float sx = rbuf[8] + rbuf[9] + rbuf[10] + rbuf[11];
        float sy = rbuf[12] + rbuf[13] + rbuf[14] + rbuf[15];
        float gx = sx / s0, gy = sy / s0;
        float mx = (gx + 1.f) * 31.5f;
        float my = (gy + 1.f) * 31.5f;
        out[(((size_t)b * 2 + 0) * 64 + typ) * 64 + txp] = mx - (float)txp;
        out[(((size_t)b * 2 + 1) * 64 + typ) * 64 + txp] = my - (float)typ;
    }
}

// ---------------------------------------------------------------------------
// Workspace (float units), total 8,675,328 = 33.09 MiB (< proven 33.47):
//   corrT 4,194,304 (ctxpar aliases: 1,835,008)
//   yh 2,097,152 (pparts aliases: 32,768) | yl 2,097,152
//   nrm_parts 32,768 | nrm_sq 8,192 | smax 4,096 | tmax 4,096 | pnorm 8,192
//   ctxbuf 229,376 (tpar 131,072 + spar 65,536 alias it after conv chunk 3)
// ---------------------------------------------------------------------------
extern "C" void kernel_launch(void* const* d_in, const int* in_sizes, int n_in,
                              void* d_out, int out_size, void* d_ws, size_t ws_size,
                              hipStream_t stream) {
    const float* src  = (const float*)d_in[0];
    const float* tgt  = (const float*)d_in[1];
    const float* sw   = (const float*)d_in[2];
    const float* sb   = (const float*)d_in[3];
    float* out = (float*)d_out;

    float* f = (float*)d_ws;
    float*     corrT     = f;
    _Float16*  yh        = (_Float16*)(f + 4194304);
    _Float16*  yl        = (_Float16*)(f + 6291456);
    float*     nrm_parts = f + 8388608;
    float*     nrm_sq    = nrm_parts + 32768;
    float*     smax      = nrm_sq + 8192;
    float*     tmax      = smax + 4096;
    float*     pnorm     = tmax + 4096;
    float*     ctxbuf    = pnorm + 8192;
    // aliases (lifetime-disjoint)
    float*     ctxpar    = corrT;          // dead before corr MODE0
    float*     pparts    = (float*)yh;     // dead before conv chunk 0
    float*     tpar      = ctxbuf;         // ctxbuf dead after conv chunk 3
    float*     spar      = ctxbuf + 131072;

    pnorm_part<<<dim3(8, 16, 4), 64, 0, stream>>>(src, tgt, pparts);
    pnorm_combine<<<dim3(8, 16), 64, 0, stream>>>(pparts, pnorm);
    ctx_part<<<dim3(8, 32, 8), 896, 0, stream>>>(src, tgt, ctxpar);
    ctx_combine<<<dim3(4, 28, 8), 256, 0, stream>>>(ctxpar, pnorm, ctxbuf);

    conv_mfma<true><<<dim3(4, 16, 8), 256, 0, stream>>>(src, tgt, ctxbuf, sw, sb,
                                                        yh, yl, nrm_parts, 0);
    corr_mfma<0><<<dim3(32, 16, 4), 64, 0, stream>>>(yh, yl, nrm_sq, corrT, spar, tpar);
    for (int c = 1; c < 3; ++c) {
        conv_mfma<false><<<dim3(4, 16, 8), 256, 0, stream>>>(src, tgt, ctxbuf, sw, sb,
                                                             yh, yl, nrm_parts, c * CCHNK);
        corr_mfma<1><<<dim3(32, 16, 4), 64, 0, stream>>>(yh, yl, nrm_sq, corrT, spar, tpar);
    }
    conv_mfma<false><<<dim3(4, 16, 8), 256, 0, stream>>>(src, tgt, ctxbuf, sw, sb,
                                                         yh, yl, nrm_parts, 3 * CCHNK);
    nrm_reduce<<<dim3(4, 8), 256, 0, stream>>>(nrm_parts, nrm_sq);
    corr_mfma<2><<<dim3(32, 16, 4), 64, 0, stream>>>(yh, yl, nrm_sq, corrT, spar, tpar);

    combine_max<<<dim3(4, 4), 256, 0, stream>>>(spar, tpar, smax, tmax);
    final_kernel<<<dim3(64, 64, 4), 256, 0, stream>>>(corrT, smax, tmax, out);
}